// Round 8
// baseline (226.935 us; speedup 1.0000x reference)
//
#include <hip/hip_runtime.h>
#include <stdint.h>

#define N_PP   8192
#define DIM    16
#define NEDGE  262144
#define LOG2E  1.4426950408889634f

// ---- ws float-unit layout ----
// [0]=nonlink_pp [2]=nonlink_ap [4]=block-completion counter (uint)
// [5]=work-queue ticket (uint)   (all zeroed by pre, g<8)
// [8..136)  pp edge per-block sums   [136..264) ap edge per-block sums
// data regions from float 512:
#define WS_EDGE  8
#define WS_PSBF  512
#define WS_PBF   (WS_PSBF + 65536)
#define WS_ABF   (WS_PBF  + 65536)
#define WS_X2PS  (WS_ABF  + 65536)
#define WS_Y2P   (WS_X2PS + 8192)
#define WS_Y2A   (WS_Y2P  + 8192)
#define WS_EGC   (WS_Y2A  + 8192)   // exp(gamma_pp[8192+j])
#define WS_EBC   (WS_EGC  + 8192)   // exp(beta_ap[8192+j])
#define WS_GL2   (WS_EBC  + 8192)   // gamma_pp[i]*LOG2E
#define WS_BL2   (WS_GL2  + 8192)   // beta_ap[i]*LOG2E

// Work queue: quanta = (128-col group g, 256-row chunk c = 16 row-tiles).
// ap: 64 groups x 32 chunks = 2048 (popped first, heavy+uniform).
// pp: pair {2m,2m+1} needs m+1 chunks each -> 1056 (popped last, light).
// Persistent grid: 2048 blocks = 8/CU (wave-slot cap) pop until empty --
// fixes the r0 tail (occupancy 76%->28% decay: 1568 unequal blocks, no
// refill). Decode verified in r2 (absmax 0).
#define NQ_AP2  2048
#define NQ_PP2  1056
#define NQ_TOT  (NQ_AP2 + NQ_PP2)   // 3104
#define NB_PERS 2048

typedef short    bf16x8 __attribute__((ext_vector_type(8)));
typedef float    f32x4  __attribute__((ext_vector_type(4)));
typedef unsigned u32x4  __attribute__((ext_vector_type(4)));

__device__ __forceinline__ float waveReduce(float v) {
#pragma unroll
    for (int off = 32; off > 0; off >>= 1)
        v += __shfl_down(v, off, 64);
    return v;
}

__device__ __forceinline__ unsigned bf16_rne(float f) {
    unsigned u = __builtin_bit_cast(unsigned, f);
    return (u + 0x7FFFu + ((u >> 16) & 1u)) >> 16;
}
__device__ __forceinline__ unsigned packbf2(float a, float b) {
    return bf16_rne(a) | (bf16_rne(b) << 16);
}

// Async global->LDS DMA, 16 B/lane, lane i lands at ldsbase + i*16.
__device__ __forceinline__ void gload_lds(const uint32_t* g, uint32_t* l) {
    __builtin_amdgcn_global_load_lds(
        (const __attribute__((address_space(1))) void*)(uintptr_t)g,
        (__attribute__((address_space(3))) void*)(unsigned)(uintptr_t)l,
        16, 0, 0);
}

// K1: 480 blocks. [0,224): conversions + bias arrays + zero accums/queue.
// [224,480): 256 edge blocks -> pure per-block writes to ws[WS_EDGE + eb].
// (EXACT round-0 version; restructures in r1-r4 all regressed.)
__global__ __launch_bounds__(256) void pre_kernel(
    const float* __restrict__ p_star, const float* __restrict__ p,
    const float* __restrict__ a, const float* __restrict__ beta_ap,
    const float* __restrict__ gamma_pp, const int* __restrict__ edges_pp,
    const int* __restrict__ edges_ap, float* __restrict__ ws)
{
    const int b = blockIdx.x, tid = threadIdx.x;

    if (b < 224) {
        const int g = b * 256 + tid;
        if (g < 8) ws[g] = 0.0f;
        if (g < 3 * 8192) {
            const int arr = g >> 13, idx = g & 8191;
            const float* src = arr == 0 ? p_star : (arr == 1 ? p : a);
            const int bfo = arr == 0 ? WS_PSBF : (arr == 1 ? WS_PBF : WS_ABF);
            const int n2o = arr == 0 ? WS_X2PS : (arr == 1 ? WS_Y2P : WS_Y2A);
            const float4* rp = (const float4*)(src + idx * DIM);
            float4 f0 = rp[0], f1 = rp[1], f2 = rp[2], f3 = rp[3];
            float n2 = f0.x*f0.x + f0.y*f0.y + f0.z*f0.z + f0.w*f0.w
                     + f1.x*f1.x + f1.y*f1.y + f1.z*f1.z + f1.w*f1.w
                     + f2.x*f2.x + f2.y*f2.y + f2.z*f2.z + f2.w*f2.w
                     + f3.x*f3.x + f3.y*f3.y + f3.z*f3.z + f3.w*f3.w;
            u32x4 u0 = { packbf2(f0.x, f0.y), packbf2(f0.z, f0.w),
                         packbf2(f1.x, f1.y), packbf2(f1.z, f1.w) };
            u32x4 u1 = { packbf2(f2.x, f2.y), packbf2(f2.z, f2.w),
                         packbf2(f3.x, f3.y), packbf2(f3.z, f3.w) };
            u32x4* dst = (u32x4*)(ws + bfo) + idx * 2;   // 32 B/row contiguous
            dst[0] = u0; dst[1] = u1;
            ws[n2o + idx] = n2;
        } else if (g < 7 * 8192) {
            const int h = g - 3 * 8192, q = h >> 13, i = h & 8191;
            if      (q == 0) ws[WS_EGC + i] = __expf(gamma_pp[8192 + i]);
            else if (q == 1) ws[WS_EBC + i] = __expf(beta_ap[8192 + i]);
            else if (q == 2) ws[WS_GL2 + i] = gamma_pp[i] * LOG2E;
            else             ws[WS_BL2 + i] = beta_ap[i] * LOG2E;
        }
    } else {
        __shared__ float smred[4];
        const int  eb   = b - 224;            // 0..255
        const bool isPP = (eb < 128);
        const int  base = (isPP ? eb : eb - 128) * 2048;
        float sum = 0.f;
#pragma unroll
        for (int k = 0; k < 8; ++k) {
            const int e = base + k * 256 + tid;
            const float* yrow;
            float bias;
            int e0;
            if (isPP) {
                e0 = edges_pp[e];
                int e1 = edges_pp[NEDGE + e];
                yrow = p + e1 * DIM;
                bias = gamma_pp[e0] + gamma_pp[N_PP + e1];
            } else {
                e0 = edges_ap[e];
                int e1 = edges_ap[NEDGE + e];
                yrow = a + (e1 - N_PP) * DIM;
                bias = beta_ap[e0] + beta_ap[e1];
            }
            const float4* xp = (const float4*)(p_star + e0 * DIM);
            const float4* yp = (const float4*)yrow;
            float d2 = 0.f;
#pragma unroll
            for (int kk = 0; kk < 4; ++kk) {
                float4 xv = xp[kk], yv = yp[kk];
                float dx = xv.x - yv.x, dy = xv.y - yv.y,
                      dz = xv.z - yv.z, dw = xv.w - yv.w;
                d2 += dx*dx + dy*dy + dz*dz + dw*dw;
            }
            sum += bias - __builtin_amdgcn_sqrtf(d2);
        }
        float wsum = waveReduce(sum);
        if ((tid & 63) == 0) smred[tid >> 6] = wsum;
        __syncthreads();
        if (tid == 0)
            ws[WS_EDGE + eb] = smred[0] + smred[1] + smred[2] + smred[3];
    }
}

// K2: persistent work-queue version of the measured-best inner loop.
__global__ __launch_bounds__(256) void main_kernel(
    float* __restrict__ ws, float* __restrict__ out)
{
    // sbuf: [0,2048) 16 tiles x 16 rows x 8 u32; [2048,2304) x2; [2304,2560) bias
    __shared__ uint32_t sbuf[2560];   // 10240 B
    __shared__ float smred[8];
    __shared__ unsigned qsh;
    const int tid = threadIdx.x, wid = tid >> 6;
    const int lane = tid & 63, quad = lane >> 4, l16 = lane & 15;

    const uint32_t* Xbf = (const uint32_t*)(ws + WS_PSBF);
    const float* x2a = ws + WS_X2PS;
    const f32x4 zero4 = {0.f, 0.f, 0.f, 0.f};

    float accPP = 0.f, accAP = 0.f;   // per-lane, carried across quanta

    for (;;) {
        __syncthreads();              // prior quantum's sbuf reads + qsh read done
        if (tid == 0) qsh = atomicAdd((unsigned*)(ws + 5), 1u);
        __syncthreads();
        const unsigned q = qsh;
        if (q >= NQ_TOT) break;       // uniform across block

        // ---- decode quantum -> (isPP, group g, chunk c) ----
        const bool isPP = (q >= NQ_AP2);
        int g, c;
        if (!isPP) { g = q >> 5; c = q & 31; }
        else {
            const int qq = q - NQ_AP2;
            int m = 0;
            while ((m + 1) * (m + 2) <= qq) ++m;   // pair band {2m, 2m+1}
            const int r = qq - m * (m + 1);
            g = 2 * m + r / (m + 1);
            c = r % (m + 1);
        }
        const int t0 = c << 4;        // global 16-row tile base

        const uint32_t* Ybf = (const uint32_t*)(ws + (isPP ? WS_PBF : WS_ABF));
        const float* y2  = ws + (isPP ? WS_Y2P : WS_Y2A);
        const float* gl2 = ws + (isPP ? WS_GL2 : WS_BL2);
        const float* EcA = ws + (isPP ? WS_EGC : WS_EBC);

        // ---- per-wave: two adjacent 16-col strips ----
        const int sA = (g << 3) + (wid << 1);
        bf16x8 bfrag[2];
        float  y2c[2], Ec[2];
#pragma unroll
        for (int ss = 0; ss < 2; ++ss) {
            const int j = ((sA + ss) << 4) + l16;
            u32x4 bu = {0u, 0u, 0u, 0u};
            if (quad < 2) bu = *(const u32x4*)(Ybf + j * 8 + (quad << 2));
            bfrag[ss] = __builtin_bit_cast(bf16x8, bu);
            y2c[ss] = y2[j];
            Ec[ss]  = EcA[j];
        }

        // ---- stage 16 tiles (8 KB rows + 1 KB x2 + 1 KB bias), async DMA ----
        for (int k = wid; k < 10; k += 4) {
            const uint32_t* gsrc;
            int loff;
            if (k < 8)       { gsrc = Xbf + (c << 11) + (k << 8); loff = k << 8; }
            else if (k == 8) { gsrc = (const uint32_t*)(x2a + (c << 8)); loff = 2048; }
            else             { gsrc = (const uint32_t*)(gl2 + (c << 8)); loff = 2304; }
            gload_lds(gsrc + (lane << 2), &sbuf[loff]);
        }
        __syncthreads();   // drains DMA, staging visible

        float acc[2] = {0.f, 0.f};
        const int tEnd = t0 + 16;
        const int tHi  = isPP ? (sA + 2 < tEnd ? sA + 2 : tEnd) : tEnd;
        for (int t = t0; t < tHi; ++t) {
            const int tl = t - t0;
            // aliased unconditional b128: quads 2,3 re-read quads 0,1's valid
            // finite data; multiplies bfrag's zero upper half -> contributes 0.
            const u32x4 au = *(const u32x4*)&sbuf[(tl << 7) + (l16 << 3) + ((quad & 1) << 2)];
            const f32x4 x24 = *(const f32x4*)((const float*)sbuf + 2048 + (tl << 4) + (quad << 2));
            const f32x4 ag4 = *(const f32x4*)((const float*)sbuf + 2304 + (tl << 4) + (quad << 2));
#pragma unroll
            for (int ss = 0; ss < 2; ++ss) {
                const int s = sA + ss;
                if (isPP && t > s) continue;            // wave-uniform
                f32x4 d = __builtin_amdgcn_mfma_f32_16x16x32_bf16(
                    __builtin_bit_cast(bf16x8, au), bfrag[ss], zero4, 0, 0, 0);
                if (!isPP || t < s) {                   // full tile
#pragma unroll
                    for (int r = 0; r < 4; ++r) {
                        float d2 = fmaf(-2.f, d[r], x24[r] + y2c[ss]);
                        d2 = fmaxf(d2, 0.f);
                        acc[ss] += __builtin_amdgcn_exp2f(
                            fmaf(-LOG2E, __builtin_amdgcn_sqrtf(d2), ag4[r]));
                    }
                } else {                                // diagonal tile, strict j>i
#pragma unroll
                    for (int r = 0; r < 4; ++r) {
                        float d2 = fmaf(-2.f, d[r], x24[r] + y2c[ss]);
                        d2 = fmaxf(d2, 0.f);
                        float term = __builtin_amdgcn_exp2f(
                            fmaf(-LOG2E, __builtin_amdgcn_sqrtf(d2), ag4[r]));
                        if (l16 <= (quad << 2) + r) term = 0.f;
                        acc[ss] += term;
                    }
                }
            }
        }
        const float v = acc[0] * Ec[0] + acc[1] * Ec[1];
        if (isPP) accPP += v; else accAP += v;
    }

    // ---- single block-level reduction + 2 atomics (r6 lesson: no per-wave
    // same-address atomic bursts) ----
    const float wPP = waveReduce(accPP);
    const float wAP = waveReduce(accAP);
    if (lane == 0) { smred[wid] = wPP; smred[4 + wid] = wAP; }
    __syncthreads();
    if (tid == 0) {
        atomicAdd(&ws[0], smred[0] + smred[1] + smred[2] + smred[3]);
        atomicAdd(&ws[2], smred[4] + smred[5] + smred[6] + smred[7]);
        __threadfence();
        unsigned old = atomicAdd((unsigned*)(ws + 4), 1u);
        if (old == NB_PERS - 1) {
            float s0 = atomicAdd(&ws[0], 0.f);    // nonlink_pp
            float s2 = atomicAdd(&ws[2], 0.f);    // nonlink_ap
            float lpp = 0.f, lap = 0.f;
            for (int i = 0; i < 128; i += 4) {
                const float4 v = *(const float4*)(ws + WS_EDGE + i);
                const float4 u = *(const float4*)(ws + WS_EDGE + 128 + i);
                lpp += v.x + v.y + v.z + v.w;
                lap += u.x + u.y + u.z + u.w;
            }
            out[0] = 0.5f * (s0 - lpp) / (float)N_PP
                   + 0.5f * (s2 - lap) / (float)N_PP;
        }
    }
}

extern "C" void kernel_launch(void* const* d_in, const int* in_sizes, int n_in,
                              void* d_out, int out_size, void* d_ws, size_t ws_size,
                              hipStream_t stream) {
    const float* p_star   = (const float*)d_in[0];
    const float* p        = (const float*)d_in[1];
    const float* a        = (const float*)d_in[2];
    const float* beta_ap  = (const float*)d_in[3];
    const float* gamma_pp = (const float*)d_in[4];
    const int*   edges_pp = (const int*)d_in[5];
    const int*   edges_ap = (const int*)d_in[6];

    float* ws  = (float*)d_ws;
    float* out = (float*)d_out;

    hipLaunchKernelGGL(pre_kernel, dim3(480), dim3(256), 0, stream,
                       p_star, p, a, beta_ap, gamma_pp, edges_pp, edges_ap, ws);
    hipLaunchKernelGGL(main_kernel, dim3(NB_PERS), dim3(256), 0, stream, ws, out);
}

// Round 9
// 172.651 us; speedup vs baseline: 1.3144x; 1.3144x over previous
//
#include <hip/hip_runtime.h>
#include <stdint.h>

#define N_PP   8192
#define DIM    16
#define NEDGE  262144
#define LOG2E  1.4426950408889634f

// ---- ws float-unit layout ----
// [0]=nonlink_pp [2]=nonlink_ap [4]=counter(uint)
// [8..136)  pp edge per-block sums (pure writes, no init needed)
// [136..264) ap edge per-block sums
// data regions from float 512:
#define WS_EDGE  8
#define WS_PSBF  512
#define WS_PBF   (WS_PSBF + 65536)
#define WS_ABF   (WS_PBF  + 65536)
#define WS_X2PS  (WS_ABF  + 65536)
#define WS_Y2P   (WS_X2PS + 8192)
#define WS_Y2A   (WS_Y2P  + 8192)
#define WS_EGC   (WS_Y2A  + 8192)   // exp(gamma_pp[8192+j])
#define WS_EBC   (WS_EGC  + 8192)   // exp(beta_ap[8192+j])
#define WS_GL2   (WS_EBC  + 8192)   // gamma_pp[i]*LOG2E
#define WS_BL2   (WS_GL2  + 8192)   // beta_ap[i]*LOG2E

// Main grid: STATIC, one block = one quantum = (128-col group g, 256-row
// chunk c of 16 row-tiles). ap: 64 groups x 32 chunks = 2048. pp: pair band
// {2m,2m+1} needs m+1 chunks each -> 1056. 3104 blocks = 12.1/CU: 8 resident
// (wave-slot cap) + ~4 queued -> hardware refill through the drain, vs r0's
// 6.1/CU all-resident-no-refill. Decode verified r2 (absmax 0). No queue
// atomics (r8 lesson), no fused edges (r1-r3 lesson).
#define NQ_AP2  2048
#define NQ_PP2  1056
#define NB_MAT  (NQ_AP2 + NQ_PP2)   // 3104

typedef short    bf16x8 __attribute__((ext_vector_type(8)));
typedef float    f32x4  __attribute__((ext_vector_type(4)));
typedef unsigned u32x4  __attribute__((ext_vector_type(4)));

__device__ __forceinline__ float waveReduce(float v) {
#pragma unroll
    for (int off = 32; off > 0; off >>= 1)
        v += __shfl_down(v, off, 64);
    return v;
}

__device__ __forceinline__ unsigned bf16_rne(float f) {
    unsigned u = __builtin_bit_cast(unsigned, f);
    return (u + 0x7FFFu + ((u >> 16) & 1u)) >> 16;
}
__device__ __forceinline__ unsigned packbf2(float a, float b) {
    return bf16_rne(a) | (bf16_rne(b) << 16);
}

// Async global->LDS DMA, 16 B/lane, lane i lands at ldsbase + i*16.
__device__ __forceinline__ void gload_lds(const uint32_t* g, uint32_t* l) {
    __builtin_amdgcn_global_load_lds(
        (const __attribute__((address_space(1))) void*)(uintptr_t)g,
        (__attribute__((address_space(3))) void*)(unsigned)(uintptr_t)l,
        16, 0, 0);
}

// K1: 480 blocks. [0,224): conversions + bias arrays + zero accums.
// [224,480): 256 edge blocks (128 pp + 128 ap, 2048 edges each) -> pure
// per-block writes to ws[WS_EDGE + eb].  (EXACT round-0 version. Edge phase
// is per-CU gather-throughput-bound ~18us, invariant to block count: r8's
// 1024-block variant measured identical rest.)
__global__ __launch_bounds__(256) void pre_kernel(
    const float* __restrict__ p_star, const float* __restrict__ p,
    const float* __restrict__ a, const float* __restrict__ beta_ap,
    const float* __restrict__ gamma_pp, const int* __restrict__ edges_pp,
    const int* __restrict__ edges_ap, float* __restrict__ ws)
{
    const int b = blockIdx.x, tid = threadIdx.x;

    if (b < 224) {
        const int g = b * 256 + tid;
        if (g < 8) ws[g] = 0.0f;
        if (g < 3 * 8192) {
            const int arr = g >> 13, idx = g & 8191;
            const float* src = arr == 0 ? p_star : (arr == 1 ? p : a);
            const int bfo = arr == 0 ? WS_PSBF : (arr == 1 ? WS_PBF : WS_ABF);
            const int n2o = arr == 0 ? WS_X2PS : (arr == 1 ? WS_Y2P : WS_Y2A);
            const float4* rp = (const float4*)(src + idx * DIM);
            float4 f0 = rp[0], f1 = rp[1], f2 = rp[2], f3 = rp[3];
            float n2 = f0.x*f0.x + f0.y*f0.y + f0.z*f0.z + f0.w*f0.w
                     + f1.x*f1.x + f1.y*f1.y + f1.z*f1.z + f1.w*f1.w
                     + f2.x*f2.x + f2.y*f2.y + f2.z*f2.z + f2.w*f2.w
                     + f3.x*f3.x + f3.y*f3.y + f3.z*f3.z + f3.w*f3.w;
            u32x4 u0 = { packbf2(f0.x, f0.y), packbf2(f0.z, f0.w),
                         packbf2(f1.x, f1.y), packbf2(f1.z, f1.w) };
            u32x4 u1 = { packbf2(f2.x, f2.y), packbf2(f2.z, f2.w),
                         packbf2(f3.x, f3.y), packbf2(f3.z, f3.w) };
            u32x4* dst = (u32x4*)(ws + bfo) + idx * 2;   // 32 B/row contiguous
            dst[0] = u0; dst[1] = u1;
            ws[n2o + idx] = n2;
        } else if (g < 7 * 8192) {
            const int h = g - 3 * 8192, q = h >> 13, i = h & 8191;
            if      (q == 0) ws[WS_EGC + i] = __expf(gamma_pp[8192 + i]);
            else if (q == 1) ws[WS_EBC + i] = __expf(beta_ap[8192 + i]);
            else if (q == 2) ws[WS_GL2 + i] = gamma_pp[i] * LOG2E;
            else             ws[WS_BL2 + i] = beta_ap[i] * LOG2E;
        }
    } else {
        __shared__ float smred[4];
        const int  eb   = b - 224;            // 0..255
        const bool isPP = (eb < 128);
        const int  base = (isPP ? eb : eb - 128) * 2048;
        float sum = 0.f;
#pragma unroll
        for (int k = 0; k < 8; ++k) {
            const int e = base + k * 256 + tid;
            const float* yrow;
            float bias;
            int e0;
            if (isPP) {
                e0 = edges_pp[e];
                int e1 = edges_pp[NEDGE + e];
                yrow = p + e1 * DIM;
                bias = gamma_pp[e0] + gamma_pp[N_PP + e1];
            } else {
                e0 = edges_ap[e];
                int e1 = edges_ap[NEDGE + e];
                yrow = a + (e1 - N_PP) * DIM;
                bias = beta_ap[e0] + beta_ap[e1];
            }
            const float4* xp = (const float4*)(p_star + e0 * DIM);
            const float4* yp = (const float4*)yrow;
            float d2 = 0.f;
#pragma unroll
            for (int kk = 0; kk < 4; ++kk) {
                float4 xv = xp[kk], yv = yp[kk];
                float dx = xv.x - yv.x, dy = xv.y - yv.y,
                      dz = xv.z - yv.z, dw = xv.w - yv.w;
                d2 += dx*dx + dy*dy + dz*dz + dw*dw;
            }
            sum += bias - __builtin_amdgcn_sqrtf(d2);
        }
        float wsum = waveReduce(sum);
        if ((tid & 63) == 0) smred[tid >> 6] = wsum;
        __syncthreads();
        if (tid == 0)
            ws[WS_EDGE + eb] = smred[0] + smred[1] + smred[2] + smred[3];
    }
}

// K2: r0 inner loop, 256-row chunks, static 3104-block grid (refill).
__global__ __launch_bounds__(256) void main_kernel(
    float* __restrict__ ws, float* __restrict__ out)
{
    // sbuf: [0,2048) 16 tiles x 16 rows x 8 u32; [2048,2304) x2; [2304,2560) bias
    __shared__ uint32_t sbuf[2560];   // 10240 B; reduction scratch aliased in
    const int b = blockIdx.x, tid = threadIdx.x, wid = tid >> 6;
    const int lane = tid & 63, quad = lane >> 4, l16 = lane & 15;

    // ---- decode quantum -> (isPP, group g, chunk c) ----
    const bool isPP = (b >= NQ_AP2);
    int g, c;
    if (!isPP) { g = b >> 5; c = b & 31; }
    else {
        const int qq = b - NQ_AP2;
        int m = 0;
        while ((m + 1) * (m + 2) <= qq) ++m;   // pair band {2m, 2m+1}
        const int r = qq - m * (m + 1);
        g = 2 * m + r / (m + 1);
        c = r % (m + 1);
    }
    const int t0 = c << 4;                     // global 16-row tile base

    const uint32_t* Xbf = (const uint32_t*)(ws + WS_PSBF);
    const uint32_t* Ybf = (const uint32_t*)(ws + (isPP ? WS_PBF : WS_ABF));
    const float* x2a = ws + WS_X2PS;
    const float* y2  = ws + (isPP ? WS_Y2P : WS_Y2A);
    const float* gl2 = ws + (isPP ? WS_GL2 : WS_BL2);
    const float* EcA = ws + (isPP ? WS_EGC : WS_EBC);

    // ---- per-wave: two adjacent 16-col strips ----
    const int sA = (g << 3) + (wid << 1);
    bf16x8 bfrag[2];
    float  y2c[2], Ec[2];
#pragma unroll
    for (int ss = 0; ss < 2; ++ss) {
        const int j = ((sA + ss) << 4) + l16;
        u32x4 bu = {0u, 0u, 0u, 0u};
        if (quad < 2) bu = *(const u32x4*)(Ybf + j * 8 + (quad << 2));
        bfrag[ss] = __builtin_bit_cast(bf16x8, bu);
        y2c[ss] = y2[j];
        Ec[ss]  = EcA[j];
    }

    // ---- stage 16 tiles (8 KB rows + 1 KB x2 + 1 KB bias), async DMA ----
    for (int k = wid; k < 10; k += 4) {
        const uint32_t* gsrc;
        int loff;
        if (k < 8)       { gsrc = Xbf + (c << 11) + (k << 8); loff = k << 8; }
        else if (k == 8) { gsrc = (const uint32_t*)(x2a + (c << 8)); loff = 2048; }
        else             { gsrc = (const uint32_t*)(gl2 + (c << 8)); loff = 2304; }
        gload_lds(gsrc + (lane << 2), &sbuf[loff]);
    }
    __syncthreads();   // drains DMA, staging visible

    const f32x4 zero4 = {0.f, 0.f, 0.f, 0.f};
    float acc[2] = {0.f, 0.f};
    const int tEnd = t0 + 16;
    const int tHi  = isPP ? (sA + 2 < tEnd ? sA + 2 : tEnd) : tEnd;
    for (int t = t0; t < tHi; ++t) {
        const int tl = t - t0;
        // aliased unconditional b128: quads 2,3 re-read quads 0,1's valid
        // finite data; it multiplies bfrag's zero upper half -> contributes 0.
        const u32x4 au = *(const u32x4*)&sbuf[(tl << 7) + (l16 << 3) + ((quad & 1) << 2)];
        const f32x4 x24 = *(const f32x4*)((const float*)sbuf + 2048 + (tl << 4) + (quad << 2));
        const f32x4 ag4 = *(const f32x4*)((const float*)sbuf + 2304 + (tl << 4) + (quad << 2));
#pragma unroll
        for (int ss = 0; ss < 2; ++ss) {
            const int s = sA + ss;
            if (isPP && t > s) continue;            // wave-uniform
            f32x4 d = __builtin_amdgcn_mfma_f32_16x16x32_bf16(
                __builtin_bit_cast(bf16x8, au), bfrag[ss], zero4, 0, 0, 0);
            if (!isPP || t < s) {                   // full tile
#pragma unroll
                for (int r = 0; r < 4; ++r) {
                    float d2 = fmaf(-2.f, d[r], x24[r] + y2c[ss]);
                    d2 = fmaxf(d2, 0.f);
                    acc[ss] += __builtin_amdgcn_exp2f(
                        fmaf(-LOG2E, __builtin_amdgcn_sqrtf(d2), ag4[r]));
                }
            } else {                                // diagonal tile, strict j>i
#pragma unroll
                for (int r = 0; r < 4; ++r) {
                    float d2 = fmaf(-2.f, d[r], x24[r] + y2c[ss]);
                    d2 = fmaxf(d2, 0.f);
                    float term = __builtin_amdgcn_exp2f(
                        fmaf(-LOG2E, __builtin_amdgcn_sqrtf(d2), ag4[r]));
                    if (l16 <= (quad << 2) + r) term = 0.f;
                    acc[ss] += term;
                }
            }
        }
    }
    const float val = acc[0] * Ec[0] + acc[1] * Ec[1];

    // Block-level reduction (scratch aliased into sbuf, barrier-separated)
    // + single per-block atomic (r6/r8 lesson).
    const float wsum = waveReduce(val);
    __syncthreads();                          // all waves done reading sbuf
    float* smred = (float*)sbuf;
    if (lane == 0) smred[wid] = wsum;
    __syncthreads();
    if (tid == 0) {
        atomicAdd(&ws[isPP ? 2 : 0], smred[0] + smred[1] + smred[2] + smred[3]);
        __threadfence();
        unsigned old = atomicAdd((unsigned*)(ws + 4), 1u);
        if (old == NB_MAT - 1) {
            float s0 = atomicAdd(&ws[0], 0.f);    // nonlink_pp
            float s2 = atomicAdd(&ws[2], 0.f);    // nonlink_ap
            float lpp = 0.f, lap = 0.f;
            for (int i = 0; i < 128; i += 4) {
                const float4 v = *(const float4*)(ws + WS_EDGE + i);
                const float4 u = *(const float4*)(ws + WS_EDGE + 128 + i);
                lpp += v.x + v.y + v.z + v.w;
                lap += u.x + u.y + u.z + u.w;
            }
            out[0] = 0.5f * (s0 - lpp) / (float)N_PP
                   + 0.5f * (s2 - lap) / (float)N_PP;
        }
    }
}

extern "C" void kernel_launch(void* const* d_in, const int* in_sizes, int n_in,
                              void* d_out, int out_size, void* d_ws, size_t ws_size,
                              hipStream_t stream) {
    const float* p_star   = (const float*)d_in[0];
    const float* p        = (const float*)d_in[1];
    const float* a        = (const float*)d_in[2];
    const float* beta_ap  = (const float*)d_in[3];
    const float* gamma_pp = (const float*)d_in[4];
    const int*   edges_pp = (const int*)d_in[5];
    const int*   edges_ap = (const int*)d_in[6];

    float* ws  = (float*)d_ws;
    float* out = (float*)d_out;

    hipLaunchKernelGGL(pre_kernel, dim3(480), dim3(256), 0, stream,
                       p_star, p, a, beta_ap, gamma_pp, edges_pp, edges_ap, ws);
    hipLaunchKernelGGL(main_kernel, dim3(NB_MAT), dim3(256), 0, stream, ws, out);
}

// Round 10
// 136.688 us; speedup vs baseline: 1.6602x; 1.2631x over previous
//
#include <hip/hip_runtime.h>
#include <stdint.h>

#define N_PP   8192
#define DIM    16
#define NEDGE  262144
#define LOG2E  1.4426950408889634f

// ---- ws float-unit layout ----
// [0]=nonlink_pp [2]=nonlink_ap [4]=counter(uint)
// [8..136)  pp edge per-block sums (pure writes, no init needed)
// [136..264) ap edge per-block sums
// data regions from float 512:
#define WS_EDGE  8
#define WS_PSBF  512
#define WS_PBF   (WS_PSBF + 65536)
#define WS_ABF   (WS_PBF  + 65536)
#define WS_X2PS  (WS_ABF  + 65536)
#define WS_Y2P   (WS_X2PS + 8192)
#define WS_Y2A   (WS_Y2P  + 8192)
#define WS_EGC   (WS_Y2A  + 8192)   // exp(gamma_pp[8192+j])
#define WS_EBC   (WS_EGC  + 8192)   // exp(beta_ap[8192+j])
#define WS_GL2   (WS_EBC  + 8192)   // gamma_pp[i]*LOG2E
#define WS_BL2   (WS_GL2  + 8192)   // beta_ap[i]*LOG2E

// Main grid: one block = (256-col group g of 16 strips, 256-row chunk c of
// 16 tiles). Wave w owns 4 strips 16g+4w..+3 -- 2x the ILP of the 2-strip
// config at the same block count (1552 ~ 1568) and same 24 waves/CU TLP.
// ap: 32 groups x 32 chunks = 1024. pp: group g needs g+1 chunks -> 528.
// r9 lesson: block count (per-block fixed overhead) is the cost driver;
// this keeps it at the proven level while doubling per-wave work.
#define NQ_AP4  1024
#define NQ_PP4  528
#define NB_MAT  (NQ_AP4 + NQ_PP4)   // 1552

typedef short    bf16x8 __attribute__((ext_vector_type(8)));
typedef float    f32x4  __attribute__((ext_vector_type(4)));
typedef unsigned u32x4  __attribute__((ext_vector_type(4)));

__device__ __forceinline__ float waveReduce(float v) {
#pragma unroll
    for (int off = 32; off > 0; off >>= 1)
        v += __shfl_down(v, off, 64);
    return v;
}

__device__ __forceinline__ unsigned bf16_rne(float f) {
    unsigned u = __builtin_bit_cast(unsigned, f);
    return (u + 0x7FFFu + ((u >> 16) & 1u)) >> 16;
}
__device__ __forceinline__ unsigned packbf2(float a, float b) {
    return bf16_rne(a) | (bf16_rne(b) << 16);
}

// Async global->LDS DMA, 16 B/lane, lane i lands at ldsbase + i*16.
__device__ __forceinline__ void gload_lds(const uint32_t* g, uint32_t* l) {
    __builtin_amdgcn_global_load_lds(
        (const __attribute__((address_space(1))) void*)(uintptr_t)g,
        (__attribute__((address_space(3))) void*)(unsigned)(uintptr_t)l,
        16, 0, 0);
}

// K1: 480 blocks. [0,224): conversions + bias arrays + zero accums.
// [224,480): 256 edge blocks (128 pp + 128 ap, 2048 edges each) -> pure
// per-block writes to ws[WS_EDGE + eb].  (EXACT round-0 version; edge phase
// is per-CU gather-throughput-bound ~18us, invariant to block count (r8).)
__global__ __launch_bounds__(256) void pre_kernel(
    const float* __restrict__ p_star, const float* __restrict__ p,
    const float* __restrict__ a, const float* __restrict__ beta_ap,
    const float* __restrict__ gamma_pp, const int* __restrict__ edges_pp,
    const int* __restrict__ edges_ap, float* __restrict__ ws)
{
    const int b = blockIdx.x, tid = threadIdx.x;

    if (b < 224) {
        const int g = b * 256 + tid;
        if (g < 8) ws[g] = 0.0f;
        if (g < 3 * 8192) {
            const int arr = g >> 13, idx = g & 8191;
            const float* src = arr == 0 ? p_star : (arr == 1 ? p : a);
            const int bfo = arr == 0 ? WS_PSBF : (arr == 1 ? WS_PBF : WS_ABF);
            const int n2o = arr == 0 ? WS_X2PS : (arr == 1 ? WS_Y2P : WS_Y2A);
            const float4* rp = (const float4*)(src + idx * DIM);
            float4 f0 = rp[0], f1 = rp[1], f2 = rp[2], f3 = rp[3];
            float n2 = f0.x*f0.x + f0.y*f0.y + f0.z*f0.z + f0.w*f0.w
                     + f1.x*f1.x + f1.y*f1.y + f1.z*f1.z + f1.w*f1.w
                     + f2.x*f2.x + f2.y*f2.y + f2.z*f2.z + f2.w*f2.w
                     + f3.x*f3.x + f3.y*f3.y + f3.z*f3.z + f3.w*f3.w;
            u32x4 u0 = { packbf2(f0.x, f0.y), packbf2(f0.z, f0.w),
                         packbf2(f1.x, f1.y), packbf2(f1.z, f1.w) };
            u32x4 u1 = { packbf2(f2.x, f2.y), packbf2(f2.z, f2.w),
                         packbf2(f3.x, f3.y), packbf2(f3.z, f3.w) };
            u32x4* dst = (u32x4*)(ws + bfo) + idx * 2;   // 32 B/row contiguous
            dst[0] = u0; dst[1] = u1;
            ws[n2o + idx] = n2;
        } else if (g < 7 * 8192) {
            const int h = g - 3 * 8192, q = h >> 13, i = h & 8191;
            if      (q == 0) ws[WS_EGC + i] = __expf(gamma_pp[8192 + i]);
            else if (q == 1) ws[WS_EBC + i] = __expf(beta_ap[8192 + i]);
            else if (q == 2) ws[WS_GL2 + i] = gamma_pp[i] * LOG2E;
            else             ws[WS_BL2 + i] = beta_ap[i] * LOG2E;
        }
    } else {
        __shared__ float smred[4];
        const int  eb   = b - 224;            // 0..255
        const bool isPP = (eb < 128);
        const int  base = (isPP ? eb : eb - 128) * 2048;
        float sum = 0.f;
#pragma unroll
        for (int k = 0; k < 8; ++k) {
            const int e = base + k * 256 + tid;
            const float* yrow;
            float bias;
            int e0;
            if (isPP) {
                e0 = edges_pp[e];
                int e1 = edges_pp[NEDGE + e];
                yrow = p + e1 * DIM;
                bias = gamma_pp[e0] + gamma_pp[N_PP + e1];
            } else {
                e0 = edges_ap[e];
                int e1 = edges_ap[NEDGE + e];
                yrow = a + (e1 - N_PP) * DIM;
                bias = beta_ap[e0] + beta_ap[e1];
            }
            const float4* xp = (const float4*)(p_star + e0 * DIM);
            const float4* yp = (const float4*)yrow;
            float d2 = 0.f;
#pragma unroll
            for (int kk = 0; kk < 4; ++kk) {
                float4 xv = xp[kk], yv = yp[kk];
                float dx = xv.x - yv.x, dy = xv.y - yv.y,
                      dz = xv.z - yv.z, dw = xv.w - yv.w;
                d2 += dx*dx + dy*dy + dz*dz + dw*dw;
            }
            sum += bias - __builtin_amdgcn_sqrtf(d2);
        }
        float wsum = waveReduce(sum);
        if ((tid & 63) == 0) smred[tid >> 6] = wsum;
        __syncthreads();
        if (tid == 0)
            ws[WS_EDGE + eb] = smred[0] + smred[1] + smred[2] + smred[3];
    }
}

// K2: 4-strip/wave variant of the measured-best inner loop.
__global__ void main_kernel(float* __restrict__ ws, float* __restrict__ out)
{
    // sbuf: [0,2048) 16 tiles x 16 rows x 8 u32; [2048,2304) x2; [2304,2560) bias
    __shared__ uint32_t sbuf[2560];   // 10240 B; reduction scratch aliased in
    const int b = blockIdx.x, tid = threadIdx.x, wid = tid >> 6;
    const int lane = tid & 63, quad = lane >> 4, l16 = lane & 15;

    // ---- decode quantum -> (isPP, group g, chunk c) ----
    const bool isPP = (b >= NQ_AP4);
    int g, c;
    if (!isPP) { g = b >> 5; c = b & 31; }
    else {
        const int qq = b - NQ_AP4;
        int m = 0;
        while ((m + 1) * (m + 2) / 2 <= qq) ++m;   // group g has g+1 chunks
        g = m; c = qq - m * (m + 1) / 2;
    }
    const int t0 = c << 4;                     // global 16-row tile base

    const uint32_t* Xbf = (const uint32_t*)(ws + WS_PSBF);
    const uint32_t* Ybf = (const uint32_t*)(ws + (isPP ? WS_PBF : WS_ABF));
    const float* x2a = ws + WS_X2PS;
    const float* y2  = ws + (isPP ? WS_Y2P : WS_Y2A);
    const float* gl2 = ws + (isPP ? WS_GL2 : WS_BL2);
    const float* EcA = ws + (isPP ? WS_EGC : WS_EBC);

    // ---- per-wave: FOUR adjacent 16-col strips ----
    const int sA = (g << 4) + (wid << 2);
    bf16x8 bfrag[4];
    float  y2c[4], Ec[4];
#pragma unroll
    for (int ss = 0; ss < 4; ++ss) {
        const int j = ((sA + ss) << 4) + l16;
        u32x4 bu = {0u, 0u, 0u, 0u};
        if (quad < 2) bu = *(const u32x4*)(Ybf + j * 8 + (quad << 2));
        bfrag[ss] = __builtin_bit_cast(bf16x8, bu);
        y2c[ss] = y2[j];
        Ec[ss]  = EcA[j];
    }

    // ---- stage 16 tiles (8 KB rows + 1 KB x2 + 1 KB bias), async DMA ----
    for (int k = wid; k < 10; k += 4) {
        const uint32_t* gsrc;
        int loff;
        if (k < 8)       { gsrc = Xbf + (c << 11) + (k << 8); loff = k << 8; }
        else if (k == 8) { gsrc = (const uint32_t*)(x2a + (c << 8)); loff = 2048; }
        else             { gsrc = (const uint32_t*)(gl2 + (c << 8)); loff = 2304; }
        gload_lds(gsrc + (lane << 2), &sbuf[loff]);
    }
    __syncthreads();   // drains DMA, staging visible

    const f32x4 zero4 = {0.f, 0.f, 0.f, 0.f};
    float acc[4] = {0.f, 0.f, 0.f, 0.f};
    const int tEnd = t0 + 16;
    const int tHi  = isPP ? (sA + 4 < tEnd ? sA + 4 : tEnd) : tEnd;
    for (int t = t0; t < tHi; ++t) {
        const int tl = t - t0;
        // aliased unconditional b128: quads 2,3 re-read quads 0,1's valid
        // finite data; it multiplies bfrag's zero upper half -> contributes 0.
        const u32x4 au = *(const u32x4*)&sbuf[(tl << 7) + (l16 << 3) + ((quad & 1) << 2)];
        const f32x4 x24 = *(const f32x4*)((const float*)sbuf + 2048 + (tl << 4) + (quad << 2));
        const f32x4 ag4 = *(const f32x4*)((const float*)sbuf + 2304 + (tl << 4) + (quad << 2));
#pragma unroll
        for (int ss = 0; ss < 4; ++ss) {
            const int s = sA + ss;
            if (isPP && t > s) continue;            // wave-uniform
            f32x4 d = __builtin_amdgcn_mfma_f32_16x16x32_bf16(
                __builtin_bit_cast(bf16x8, au), bfrag[ss], zero4, 0, 0, 0);
            if (!isPP || t < s) {                   // full tile
#pragma unroll
                for (int r = 0; r < 4; ++r) {
                    float d2 = fmaf(-2.f, d[r], x24[r] + y2c[ss]);
                    d2 = fmaxf(d2, 0.f);
                    acc[ss] += __builtin_amdgcn_exp2f(
                        fmaf(-LOG2E, __builtin_amdgcn_sqrtf(d2), ag4[r]));
                }
            } else {                                // diagonal tile, strict j>i
#pragma unroll
                for (int r = 0; r < 4; ++r) {
                    float d2 = fmaf(-2.f, d[r], x24[r] + y2c[ss]);
                    d2 = fmaxf(d2, 0.f);
                    float term = __builtin_amdgcn_exp2f(
                        fmaf(-LOG2E, __builtin_amdgcn_sqrtf(d2), ag4[r]));
                    if (l16 <= (quad << 2) + r) term = 0.f;
                    acc[ss] += term;
                }
            }
        }
    }
    const float val = acc[0] * Ec[0] + acc[1] * Ec[1]
                    + acc[2] * Ec[2] + acc[3] * Ec[3];

    // Block-level reduction (scratch aliased into sbuf, barrier-separated)
    // + single per-block atomic (r6/r8 lesson).
    const float wsum = waveReduce(val);
    __syncthreads();                          // all waves done reading sbuf
    float* smred = (float*)sbuf;
    if (lane == 0) smred[wid] = wsum;
    __syncthreads();
    if (tid == 0) {
        atomicAdd(&ws[isPP ? 2 : 0], smred[0] + smred[1] + smred[2] + smred[3]);
        __threadfence();
        unsigned old = atomicAdd((unsigned*)(ws + 4), 1u);
        if (old == NB_MAT - 1) {
            float s0 = atomicAdd(&ws[0], 0.f);    // nonlink_pp
            float s2 = atomicAdd(&ws[2], 0.f);    // nonlink_ap
            float lpp = 0.f, lap = 0.f;
            for (int i = 0; i < 128; i += 4) {
                const float4 v = *(const float4*)(ws + WS_EDGE + i);
                const float4 u = *(const float4*)(ws + WS_EDGE + 128 + i);
                lpp += v.x + v.y + v.z + v.w;
                lap += u.x + u.y + u.z + u.w;
            }
            out[0] = 0.5f * (s0 - lpp) / (float)N_PP
                   + 0.5f * (s2 - lap) / (float)N_PP;
        }
    }
}

extern "C" void kernel_launch(void* const* d_in, const int* in_sizes, int n_in,
                              void* d_out, int out_size, void* d_ws, size_t ws_size,
                              hipStream_t stream) {
    const float* p_star   = (const float*)d_in[0];
    const float* p        = (const float*)d_in[1];
    const float* a        = (const float*)d_in[2];
    const float* beta_ap  = (const float*)d_in[3];
    const float* gamma_pp = (const float*)d_in[4];
    const int*   edges_pp = (const int*)d_in[5];
    const int*   edges_ap = (const int*)d_in[6];

    float* ws  = (float*)d_ws;
    float* out = (float*)d_out;

    hipLaunchKernelGGL(pre_kernel, dim3(480), dim3(256), 0, stream,
                       p_star, p, a, beta_ap, gamma_pp, edges_pp, edges_ap, ws);
    hipLaunchKernelGGL(main_kernel, dim3(NB_MAT), dim3(256), 0, stream, ws, out);
}